// Round 7
// baseline (203.040 us; speedup 1.0000x reference)
//
#include <hip/hip_runtime.h>
#include <cstdint>

// B=8, T=1024, D=1024, H=16, hd=64
// prep (fused) -> QKV GEMM (proven 128^2 2-phase) -> fused flash attention
// (swapped-QK in-register softmax, 2-kt rounds / 4-deep K/V ring) -> proj.
//
// r7 delta (attn only; everything else r6-exact):
//  - K/V LDS ring deepened 2 -> 4 slots (72 KB total; still 2 blocks/CU).
//    Each round stages tiles kt+2,kt+3 then computes kt,kt+1 then ONE
//    __syncthreads: barrier count halved (14.5 -> ~7.3/block), staged loads
//    get a 2-tile compute window, and the two tile bodies between barriers
//    are independent -> compiler can overlap kt's PV with kt+1's QK.
//    Slot liveness: slot (kt+2)&3 was last read in the previous round,
//    released by the barrier that ended it.

typedef __attribute__((ext_vector_type(8))) short bf16x8;
typedef __attribute__((ext_vector_type(4))) float f32x4;

__device__ __forceinline__ short f2b(float x) {
  unsigned u = __builtin_bit_cast(unsigned, x);
  u += 0x7fffu + ((u >> 16) & 1u);
  return (short)(u >> 16);
}

__device__ __forceinline__ unsigned cvtpk(float lo, float hi) {
  unsigned d;
  asm("v_cvt_pk_bf16_f32 %0, %1, %2" : "=v"(d) : "v"(lo), "v"(hi));
  return d;
}

__device__ __forceinline__ void gl2lds16(short* l, const short* g) {
  __builtin_amdgcn_global_load_lds(
      (const __attribute__((address_space(1))) void*)g,
      (__attribute__((address_space(3))) void*)l, 16, 0, 0);
}

// ---------------- fused prep ----------------
// blocks [0,8192): f32->bf16 convert of x (float4/short4 vectorized)
// blocks [8192,11264): transpose W_attn [1024][3072] -> [3072][1024] bf16
// blocks [11264,12288): transpose W_proj [1024][1024] -> [1024][1024] bf16

__global__ void prep_fused(const float* __restrict__ x, short* __restrict__ xb,
                           const float* __restrict__ Wa, short* __restrict__ WaT,
                           const float* __restrict__ Wp, short* __restrict__ WpT) {
  __shared__ float tile[32][33];
  const int bid = blockIdx.x;
  const int t = threadIdx.x;
  if (bid < 8192) {
    int i = bid * 256 + t;
    float4 v = ((const float4*)x)[i];
    short4 o;
    o.x = f2b(v.x); o.y = f2b(v.y); o.z = f2b(v.z); o.w = f2b(v.w);
    ((short4*)xb)[i] = o;
    return;
  }
  const float* in;
  short* out;
  int C, bx, by;
  if (bid < 11264) {
    int id = bid - 8192;
    in = Wa; out = WaT; C = 3072; bx = id % 96; by = id / 96;
  } else {
    int id = bid - 11264;
    in = Wp; out = WpT; C = 1024; bx = id % 32; by = id / 32;
  }
  const int R = 1024;
  int c0 = bx * 32, r0 = by * 32;
  int tx = t & 31, ty = t >> 5;  // 32 x 8
#pragma unroll
  for (int i = 0; i < 32; i += 8)
    tile[ty + i][tx] = in[(long)(r0 + ty + i) * C + c0 + tx];
  __syncthreads();
#pragma unroll
  for (int i = 0; i < 32; i += 8)
    out[(long)(c0 + ty + i) * R + r0 + tx] = f2b(tile[tx][ty + i]);
}

// ---------------- GEMM: C[M,N] = A[M,K] * Bt[N,K]^T + bias ----------------

template <int EPI>
__global__ __launch_bounds__(256, 3) void gemm_bt(
    const short* __restrict__ A, const short* __restrict__ Bt,
    const float* __restrict__ bias, float* __restrict__ outF,
    short* __restrict__ qh, short* __restrict__ kh, short* __restrict__ vT,
    int M, int N, int K) {
  __shared__ short At[128 * 64];
  __shared__ short Bl[128 * 64];
  const int t = threadIdx.x;
  const int wave = t >> 6, lane = t & 63;
  const int quad = lane >> 4, l15 = lane & 15;
  const int wr = wave >> 1, wc = wave & 1;
  const int m0 = blockIdx.y * 128, n0 = blockIdx.x * 128;

  f32x4 acc[4][4] = {};

  const int srow = t >> 3;
  const int sch0 = t & 7;

  for (int k0 = 0; k0 < K; k0 += 64) {
    __syncthreads();
#pragma unroll
    for (int c = 0; c < 4; ++c) {
      int row = c * 32 + srow;
      int ch = sch0 ^ (row & 7);
      gl2lds16(At + (c * 256 + t) * 8, A + (long)(m0 + row) * K + k0 + ch * 8);
      gl2lds16(Bl + (c * 256 + t) * 8, Bt + (long)(n0 + row) * K + k0 + ch * 8);
    }
    asm volatile("s_waitcnt vmcnt(0)" ::: "memory");
    __syncthreads();

#pragma unroll
    for (int s = 0; s < 2; ++s) {
      const int cx = (s * 4 + quad) ^ (l15 & 7);
      bf16x8 af[4], bfr[4];
#pragma unroll
      for (int i = 0; i < 4; ++i)
        af[i] = *(const bf16x8*)(At + (wr * 64 + i * 16 + l15) * 64 + cx * 8);
#pragma unroll
      for (int j = 0; j < 4; ++j)
        bfr[j] = *(const bf16x8*)(Bl + (wc * 64 + j * 16 + l15) * 64 + cx * 8);
#pragma unroll
      for (int i = 0; i < 4; ++i)
#pragma unroll
        for (int j = 0; j < 4; ++j)
          acc[i][j] = __builtin_amdgcn_mfma_f32_16x16x32_bf16(af[i], bfr[j],
                                                              acc[i][j], 0, 0, 0);
    }
  }

  if (EPI == 1) {
#pragma unroll
    for (int j = 0; j < 4; ++j) {
      int col = n0 + wc * 64 + j * 16 + l15;
      float bv = bias[col];
#pragma unroll
      for (int i = 0; i < 4; ++i)
#pragma unroll
        for (int r = 0; r < 4; ++r) {
          int row = m0 + wr * 64 + i * 16 + quad * 4 + r;
          outF[(long)row * N + col] = acc[i][j][r] + bv;
        }
    }
  } else {
    const int sec = n0 >> 10;
    const int b = m0 >> 10;
    // q pre-scale: fold softmax scale * log2(e) into q.
    const float sc = (sec == 0) ? (0.125f * 1.44269504089f) : 1.0f;
#pragma unroll
    for (int j = 0; j < 4; ++j) {
      int col = n0 + wc * 64 + j * 16 + l15;
      float bv = bias[col];
      int d = col & 1023, h = d >> 6, dh = d & 63;
      if (sec == 2) {
        long base = ((long)(b * 16 + h) * 64 + dh) * 1024;
#pragma unroll
        for (int i = 0; i < 4; ++i) {
          // sigma-permuted key layout: k=16i+4*quad+r -> col'
          int tt0 = (m0 & 1023) + wr * 64 + (i >> 1) * 32 + quad * 8 + (i & 1) * 4;
          short4 v;
          v.x = f2b(acc[i][j][0] + bv);
          v.y = f2b(acc[i][j][1] + bv);
          v.z = f2b(acc[i][j][2] + bv);
          v.w = f2b(acc[i][j][3] + bv);
          *(short4*)(vT + base + tt0) = v;
        }
      } else {
        short* dst = (sec == 0) ? qh : kh;
        long hbase = ((long)(b * 16 + h) * 1024) * 64 + dh;
#pragma unroll
        for (int i = 0; i < 4; ++i)
#pragma unroll
          for (int r = 0; r < 4; ++r) {
            int tt = (m0 & 1023) + wr * 64 + i * 16 + quad * 4 + r;
            dst[hbase + (long)tt * 64] = f2b((acc[i][j][r] + bv) * sc);
          }
      }
    }
  }
}

// ---------------- fused flash attention ----------------
// grid (128, 4): x = bh (same-bh p-siblings land on the same XCD), y = p.
// Block owns q-tiles {p, 7-p, 8+p, 15-p}. Swapped QK (mfma(K,Q)): lane
// (l15,quad) holds S^T for q-row l15, keys jj*16+quad*4+r. P stays in
// registers (pi-permuted pack, cvt_pk); V stored sigma-permuted in vT so
// V fragments are identity b128 reads. P_lds: epilogue transpose only.
// 2-kt rounds over a 4-slot K/V ring; one barrier per round.

__global__ __launch_bounds__(256, 2) void attn_kernel(
    const short* __restrict__ qh, const short* __restrict__ kh,
    const short* __restrict__ vT, short* __restrict__ attout) {
  __shared__ short Kb[4][64 * 64];
  __shared__ short Vb[4][64 * 64];
  __shared__ short P_lds[4][16][64];  // epilogue staging only
  const int bh = blockIdx.x;
  const int p = blockIdx.y;  // 0..3
  const int t = threadIdx.x;
  const int wave = t >> 6, lane = t & 63, quad = lane >> 4, l15 = lane & 15;
  const short* q_head = qh + (long)bh * 1024 * 64;
  const short* k_head = kh + (long)bh * 1024 * 64;
  const short* v_head = vT + (long)bh * 64 * 1024;
  const int b_ = bh >> 4, h_ = bh & 15;

  const int qt[4] = {p, 7 - p, 8 + p, 15 - p};  // ascending

  auto stage = [&](int kt) {
    const int buf = kt & 3;
    const int kk0 = kt * 64;
#pragma unroll
    for (int i = 0; i < 2; ++i) {
      int s = i * 256 + t;
      int row = s >> 3, cg = (s & 7) ^ (row & 7);
      gl2lds16(&Kb[buf][s * 8], k_head + (kk0 + row) * 64 + cg * 8);
    }
#pragma unroll
    for (int i = 0; i < 2; ++i) {
      int s = i * 256 + t;
      int row = s >> 3, cg = (s & 7) ^ (row & 7);
      gl2lds16(&Vb[buf][s * 8], v_head + row * 1024 + kk0 + cg * 8);
    }
  };

  bf16x8 qf[4][2];
#pragma unroll
  for (int i = 0; i < 4; ++i) {
    int qb = qt[i] * 64 + wave * 16;
#pragma unroll
    for (int s = 0; s < 2; ++s)
      qf[i][s] = *(const bf16x8*)(q_head + (qb + l15) * 64 + s * 32 + quad * 8);
  }

  float l[4] = {};
  f32x4 o[4][4] = {};

  const int nkt = qt[3] + 1;  // 16 - p

  stage(0);
  if (1 < nkt) stage(1);
  __syncthreads();

  auto computeTile = [&](int kt) {
    const int buf = kt & 3;
    const short* Kt = Kb[buf];
    const short* Vt = Vb[buf];

    bf16x8 kfr[4][2], vfr[4][2];
#pragma unroll
    for (int jj = 0; jj < 4; ++jj) {
      int row = jj * 16 + l15;
#pragma unroll
      for (int s = 0; s < 2; ++s) {
        int off = ((s * 4 + quad) ^ (row & 7)) * 8;
        kfr[jj][s] = *(const bf16x8*)(Kt + row * 64 + off);
        vfr[jj][s] = *(const bf16x8*)(Vt + row * 64 + off);
      }
    }

#pragma unroll
    for (int i = 0; i < 4; ++i) {
      if (kt <= qt[i]) {
        // swapped QK: lane (l15,quad) holds S[q=l15-row][key jj*16+quad*4+r]
        f32x4 s4[4] = {};
#pragma unroll
        for (int jj = 0; jj < 4; ++jj) {
          s4[jj] = __builtin_amdgcn_mfma_f32_16x16x32_bf16(kfr[jj][0], qf[i][0],
                                                           s4[jj], 0, 0, 0);
          s4[jj] = __builtin_amdgcn_mfma_f32_16x16x32_bf16(kfr[jj][1], qf[i][1],
                                                           s4[jj], 0, 0, 0);
        }
        // softmax: q already carries 0.125*log2e -> exp2 direct
        float ev[4][4];
        float ls = 0.f;
        if (kt == qt[i]) {  // diagonal tile: causal mask (uniform branch)
          const int qg = qt[i] * 64 + wave * 16 + l15;
#pragma unroll
          for (int jj = 0; jj < 4; ++jj) {
            const int kb = kt * 64 + jj * 16 + quad * 4;
#pragma unroll
            for (int r = 0; r < 4; ++r) {
              float e = __builtin_amdgcn_exp2f(s4[jj][r]);
              if (kb + r > qg) e = 0.f;
              ev[jj][r] = e;
              ls += e;
            }
          }
        } else {
#pragma unroll
          for (int jj = 0; jj < 4; ++jj)
#pragma unroll
            for (int r = 0; r < 4; ++r) {
              float e = __builtin_amdgcn_exp2f(s4[jj][r]);
              ev[jj][r] = e;
              ls += e;
            }
        }
        l[i] += ls;
        // pi-permuted P pack: slot (s,quad,4cs+r) = key (2s+cs)*16+quad*4+r
        int4 pd0, pd1;
        pd0.x = (int)cvtpk(ev[0][0], ev[0][1]);
        pd0.y = (int)cvtpk(ev[0][2], ev[0][3]);
        pd0.z = (int)cvtpk(ev[1][0], ev[1][1]);
        pd0.w = (int)cvtpk(ev[1][2], ev[1][3]);
        pd1.x = (int)cvtpk(ev[2][0], ev[2][1]);
        pd1.y = (int)cvtpk(ev[2][2], ev[2][3]);
        pd1.z = (int)cvtpk(ev[3][0], ev[3][1]);
        pd1.w = (int)cvtpk(ev[3][2], ev[3][3]);
        bf16x8 pf0 = __builtin_bit_cast(bf16x8, pd0);
        bf16x8 pf1 = __builtin_bit_cast(bf16x8, pd1);
#pragma unroll
        for (int dj = 0; dj < 4; ++dj) {
          o[i][dj] = __builtin_amdgcn_mfma_f32_16x16x32_bf16(pf0, vfr[dj][0],
                                                             o[i][dj], 0, 0, 0);
          o[i][dj] = __builtin_amdgcn_mfma_f32_16x16x32_bf16(pf1, vfr[dj][1],
                                                             o[i][dj], 0, 0, 0);
        }
      }
    }
  };

#pragma unroll 1
  for (int kt2 = 0; kt2 < nkt; kt2 += 2) {
    // stage next round first: slots (kt2+2)&3/(kt2+3)&3 were released by the
    // barrier that ended the previous round; loads get a 2-tile window.
    if (kt2 + 2 < nkt) stage(kt2 + 2);
    if (kt2 + 3 < nkt) stage(kt2 + 3);
    computeTile(kt2);
    if (kt2 + 1 < nkt) computeTile(kt2 + 1);
    __syncthreads();  // releases this round's slots; drains staged loads
  }

  // deferred l reductions: sum partial row-sums across the 4 quads
#pragma unroll
  for (int i = 0; i < 4; ++i) {
    l[i] += __shfl_xor(l[i], 16);
    l[i] += __shfl_xor(l[i], 32);
  }

  // epilogue: per tile, C-layout -> rows via P_lds, then cached 16B stores.
  const int erow = lane >> 3, ech = lane & 7;
#pragma unroll
  for (int i = 0; i < 4; ++i) {
    float inv[4];
#pragma unroll
    for (int r = 0; r < 4; ++r) {
      float lr = __shfl(l[i], quad * 4 + r);  // row-sum lives in lane l15=row
      inv[r] = __builtin_amdgcn_rcpf(lr);
    }
    const int qb = qt[i] * 64 + wave * 16;
#pragma unroll
    for (int dj = 0; dj < 4; ++dj) {
      int ch = dj * 2 + (l15 >> 3), co = l15 & 7;
#pragma unroll
      for (int r = 0; r < 4; ++r) {
        int row = quad * 4 + r;
        P_lds[wave][row][(ch ^ (row & 7)) * 8 + co] = f2b(o[i][dj][r] * inv[r]);
      }
    }
    asm volatile("s_waitcnt lgkmcnt(0)" ::: "memory");
#pragma unroll
    for (int pass = 0; pass < 2; ++pass) {
      int row = pass * 8 + erow;
      bf16x8 v = *(const bf16x8*)(&P_lds[wave][row][(ech ^ (row & 7)) * 8]);
      long g = (long)b_ * 1024 + qb + row;
      *(bf16x8*)(attout + g * 1024 + h_ * 64 + ech * 8) = v;
    }
    asm volatile("s_waitcnt lgkmcnt(0)" ::: "memory");  // reads before next writes
  }
}

// ---------------- launch ----------------

extern "C" void kernel_launch(void* const* d_in, const int* in_sizes, int n_in,
                              void* d_out, int out_size, void* d_ws,
                              size_t ws_size, hipStream_t stream) {
  const float* x = (const float*)d_in[0];
  const float* W_attn = (const float*)d_in[2];
  const float* b_attn = (const float*)d_in[3];
  const float* W_proj = (const float*)d_in[4];
  const float* b_proj = (const float*)d_in[5];
  float* out = (float*)d_out;

  char* ws = (char*)d_ws;
  const size_t MB = 1u << 20;
  short* xb = (short*)(ws);              // 16 MB [0,16)
  short* WaT = (short*)(ws + 16 * MB);   // 6 MB  [16,22)
  short* WpT = (short*)(ws + 22 * MB);   // 2 MB  [22,24)
  short* qh = (short*)(ws + 24 * MB);    // 16 MB [24,40)
  short* kh = (short*)(ws + 40 * MB);    // 16 MB [40,56)
  short* vT = (short*)(ws + 56 * MB);    // 16 MB [56,72)
  short* attout = xb;                    // reuse x-bf16 region

  prep_fused<<<12288, 256, 0, stream>>>(x, xb, W_attn, WaT, W_proj, WpT);
  gemm_bt<0><<<dim3(3072 / 128, 8192 / 128), 256, 0, stream>>>(
      xb, WaT, b_attn, nullptr, qh, kh, vT, 8192, 3072, 1024);
  attn_kernel<<<dim3(128, 4), 256, 0, stream>>>(qh, kh, vT, attout);
  gemm_bt<1><<<dim3(1024 / 128, 8192 / 128), 256, 0, stream>>>(
      attout, WpT, b_proj, out, nullptr, nullptr, nullptr, 8192, 1024, 1024);
}